// Round 6
// baseline (445.170 us; speedup 1.0000x reference)
//
#include <hip/hip_runtime.h>
#include <hip/hip_bf16.h>
#include <cstdint>

#define B_ 8
#define C_ 256
#define N_ 2304
#define XT_BYTES ((size_t)B_ * N_ * C_ * 2)
#define QK_BYTES ((size_t)16 * N_ * C_ * 2)
#define V_BYTES  ((size_t)16 * C_ * N_ * 2)

typedef __bf16 bf16x8 __attribute__((ext_vector_type(8)));
typedef __bf16 bf16x4 __attribute__((ext_vector_type(4)));
typedef float  f32x4  __attribute__((ext_vector_type(4)));
static_assert(sizeof(bf16x8) == 16, "");

// async global->LDS, 16B per lane (dest = wave-uniform base + lane*16)
__device__ __forceinline__ void gload16(const void* g, void* l) {
  __builtin_amdgcn_global_load_lds(
      reinterpret_cast<const __attribute__((address_space(1))) uint32_t*>(
          reinterpret_cast<uintptr_t>(g)),
      reinterpret_cast<__attribute__((address_space(3))) uint32_t*>(
          reinterpret_cast<uintptr_t>(l)),
      16, 0, 0);
}

// ---------------------------------------------------------------------------
// Kernel 1: transpose + cvt: x[b][i][n] f32 -> xT[b][n][i] bf16, swizzled rows
// ---------------------------------------------------------------------------
__global__ __launch_bounds__(256) void k_transpose(
    const float* __restrict__ rgb, const float* __restrict__ tin,
    char* __restrict__ xT)
{
  const int nt = blockIdx.x;
  const int it = blockIdx.y;
  const int z  = blockIdx.z;
  const int src = z >> 3, b = z & 7;
  const float* __restrict__ in = (src ? tin : rgb) + (size_t)b * C_ * N_;
  char* __restrict__ out = xT + (size_t)src * XT_BYTES + (size_t)b * N_ * 512;
  const int i0 = it * 64, n0 = nt * 64;
  __shared__ float raw[64 * 65];
  const int t = threadIdx.x;
  const int rr = t >> 4;
  const int cc = t & 15;
#pragma unroll
  for (int j = 0; j < 4; ++j) {
    const int ii = rr + 16 * j;
    const float4 v = *(const float4*)(in + (size_t)(i0 + ii) * N_ + n0 + cc * 4);
    float* rp = &raw[ii * 65 + cc * 4];
    rp[0] = v.x; rp[1] = v.y; rp[2] = v.z; rp[3] = v.w;
  }
  __syncthreads();
#pragma unroll
  for (int k = 0; k < 4; ++k) {
    const int nl = rr + 16 * k;
    const int n = n0 + nl;
    union { __bf16 h[4]; uint2 u; } pk;
#pragma unroll
    for (int e = 0; e < 4; ++e)
      pk.h[e] = (__bf16)raw[(cc * 4 + e) * 65 + nl];
    const int cb = ((i0 + cc * 4) * 2) ^ ((n & 7) << 4);
    *(uint2*)(out + (size_t)n * 512 + cb) = pk.u;
  }
}

// ---------------------------------------------------------------------------
// Kernel 2: weights f32 -> bf16 swizzled rows (order wq1,wk1,wq2,wk2,wv1,wv2)
// ---------------------------------------------------------------------------
__global__ __launch_bounds__(256) void k_wcvt(
    const float* __restrict__ w0, const float* __restrict__ w1,
    const float* __restrict__ w2, const float* __restrict__ w3,
    const float* __restrict__ w4, const float* __restrict__ w5,
    char* __restrict__ Wb)
{
  const int widx = blockIdx.y;
  const float* w = widx == 0 ? w0 : widx == 1 ? w1 : widx == 2 ? w2
                 : widx == 3 ? w3 : widx == 4 ? w4 : w5;
  const int t = threadIdx.x;
  const int row = blockIdx.x * 8 + (t >> 5);
  const int c8 = (t & 31) * 8;
  const float4 v0 = *(const float4*)(w + row * 256 + c8);
  const float4 v1 = *(const float4*)(w + row * 256 + c8 + 4);
  union { __bf16 h[8]; uint4 u; } pk;
  pk.h[0] = (__bf16)v0.x; pk.h[1] = (__bf16)v0.y; pk.h[2] = (__bf16)v0.z; pk.h[3] = (__bf16)v0.w;
  pk.h[4] = (__bf16)v1.x; pk.h[5] = (__bf16)v1.y; pk.h[6] = (__bf16)v1.z; pk.h[7] = (__bf16)v1.w;
  const int cb = (c8 * 2) ^ ((row & 7) << 4);
  *(uint4*)(Wb + (size_t)(widx * 256 + row) * 512 + cb) = pk.u;
}

// ---------------------------------------------------------------------------
// Kernel 3: Q/K projection (unchanged, validated)
// ---------------------------------------------------------------------------
__global__ __launch_bounds__(256, 2) void k_proj_qk(
    const char* __restrict__ xT, const char* __restrict__ Wb,
    const float* __restrict__ bq1, const float* __restrict__ bk1,
    const float* __restrict__ bq2, const float* __restrict__ bk2,
    char* __restrict__ Qw, char* __restrict__ Kw)
{
  const int z = blockIdx.z;
  const int b = blockIdx.y;
  const int ntile = blockIdx.x >> 2, otile = blockIdx.x & 3;
  const int n0 = ntile * 128, o0 = otile * 64;
  const int srcT = (z == 1 || z == 2);
  const char* __restrict__ xp = xT + (size_t)srcT * XT_BYTES + (size_t)b * N_ * 512;
  const char* __restrict__ Wp = Wb + (size_t)z * C_ * 512;
  const float* __restrict__ bias = z == 0 ? bq1 : z == 1 ? bk1 : z == 2 ? bq2 : bk2;
  char* __restrict__ outp = ((z == 0 || z == 2) ? Qw : Kw)
                            + (size_t)((z >= 2 ? 8 : 0) + b) * N_ * 512;

  __shared__ alignas(16) char Alds[128 * 128];
  __shared__ alignas(16) char Wlds[64 * 128];
  const int t = threadIdx.x, lane = t & 63, wid = t >> 6;
  const int wm = wid >> 1, wn = wid & 1;
  const int lr = lane & 15, lk = lane >> 4;
  f32x4 acc[4][2] = {};

  for (int ko = 0; ko < 4; ++ko) {
    const int ib = ko * 128;
    __syncthreads();
#pragma unroll
    for (int s = 0; s < 4; ++s) {
      const int flat = s * 4096 + t * 16;
      *(uint4*)(Alds + flat) =
          *(const uint4*)(xp + (size_t)(n0 + (flat >> 7)) * 512 + ib + (flat & 127));
    }
#pragma unroll
    for (int s = 0; s < 2; ++s) {
      const int flat = s * 4096 + t * 16;
      *(uint4*)(Wlds + flat) =
          *(const uint4*)(Wp + (size_t)(o0 + (flat >> 7)) * 512 + ib + (flat & 127));
    }
    __syncthreads();
#pragma unroll
    for (int ks = 0; ks < 2; ++ks) {
      bf16x8 af[4], bfr[2];
#pragma unroll
      for (int mf = 0; mf < 4; ++mf) {
        const int row = wm * 64 + mf * 16 + lr;
        af[mf] = *(const bf16x8*)(Alds + row * 128 + ((ks * 64 + lk * 16) ^ ((row & 7) << 4)));
      }
#pragma unroll
      for (int nf = 0; nf < 2; ++nf) {
        const int row = wn * 32 + nf * 16 + lr;
        bfr[nf] = *(const bf16x8*)(Wlds + row * 128 + ((ks * 64 + lk * 16) ^ ((row & 7) << 4)));
      }
#pragma unroll
      for (int mf = 0; mf < 4; ++mf)
#pragma unroll
        for (int nf = 0; nf < 2; ++nf)
          acc[mf][nf] = __builtin_amdgcn_mfma_f32_16x16x32_bf16(af[mf], bfr[nf], acc[mf][nf], 0, 0, 0);
    }
  }
#pragma unroll
  for (int nf = 0; nf < 2; ++nf) {
    const int c = o0 + wn * 32 + nf * 16 + lr;
    const float bv = bias[c];
#pragma unroll
    for (int mf = 0; mf < 4; ++mf)
#pragma unroll
      for (int r = 0; r < 4; ++r) {
        const int n = n0 + wm * 64 + mf * 16 + lk * 4 + r;
        *(__bf16*)(outp + (size_t)n * 512 + ((c * 2) ^ ((n & 7) << 4))) =
            (__bf16)(acc[mf][nf][r] + bv);
      }
  }
}

// ---------------------------------------------------------------------------
// Kernel 4: V projection, stored transposed [c][n], UNSWIZZLED (validated)
// ---------------------------------------------------------------------------
__global__ __launch_bounds__(256, 2) void k_proj_v(
    const char* __restrict__ xT, const char* __restrict__ Wb,
    const float* __restrict__ bv1, const float* __restrict__ bv2,
    char* __restrict__ Vw)
{
  const int z = blockIdx.z;
  const int b = blockIdx.y;
  const int ntile = blockIdx.x >> 2, otile = blockIdx.x & 3;
  const int n0 = ntile * 128, o0 = otile * 64;
  const char* __restrict__ xp = xT + (size_t)(z == 0 ? 1 : 0) * XT_BYTES + (size_t)b * N_ * 512;
  const char* __restrict__ Wp = Wb + (size_t)(4 + z) * C_ * 512;
  const float* __restrict__ bias = z ? bv2 : bv1;
  char* __restrict__ outp = Vw + (size_t)(z * 8 + b) * C_ * 4608;

  __shared__ alignas(16) char Xlds[128 * 128];
  __shared__ alignas(16) char Wlds[64 * 128];
  const int t = threadIdx.x, lane = t & 63, wid = t >> 6;
  const int wm = wid >> 1, wn = wid & 1;
  const int lr = lane & 15, lk = lane >> 4;
  f32x4 acc[2][4] = {};

  for (int ko = 0; ko < 4; ++ko) {
    const int ib = ko * 128;
    __syncthreads();
#pragma unroll
    for (int s = 0; s < 4; ++s) {
      const int flat = s * 4096 + t * 16;
      *(uint4*)(Xlds + flat) =
          *(const uint4*)(xp + (size_t)(n0 + (flat >> 7)) * 512 + ib + (flat & 127));
    }
#pragma unroll
    for (int s = 0; s < 2; ++s) {
      const int flat = s * 4096 + t * 16;
      *(uint4*)(Wlds + flat) =
          *(const uint4*)(Wp + (size_t)(o0 + (flat >> 7)) * 512 + ib + (flat & 127));
    }
    __syncthreads();
#pragma unroll
    for (int ks = 0; ks < 2; ++ks) {
      bf16x8 af[2], bfr[4];
#pragma unroll
      for (int mf = 0; mf < 2; ++mf) {
        const int row = wm * 32 + mf * 16 + lr;
        af[mf] = *(const bf16x8*)(Wlds + row * 128 + ((ks * 64 + lk * 16) ^ ((row & 7) << 4)));
      }
#pragma unroll
      for (int nf = 0; nf < 4; ++nf) {
        const int row = wn * 64 + nf * 16 + lr;
        bfr[nf] = *(const bf16x8*)(Xlds + row * 128 + ((ks * 64 + lk * 16) ^ ((row & 7) << 4)));
      }
#pragma unroll
      for (int mf = 0; mf < 2; ++mf)
#pragma unroll
        for (int nf = 0; nf < 4; ++nf)
          acc[mf][nf] = __builtin_amdgcn_mfma_f32_16x16x32_bf16(af[mf], bfr[nf], acc[mf][nf], 0, 0, 0);
    }
  }
#pragma unroll
  for (int mf = 0; mf < 2; ++mf)
#pragma unroll
    for (int r = 0; r < 4; ++r) {
      const int o = o0 + wm * 32 + mf * 16 + lk * 4 + r;
      const float bv = bias[o];
#pragma unroll
      for (int nf = 0; nf < 4; ++nf) {
        const int n = n0 + wn * 64 + nf * 16 + lr;
        *(__bf16*)(outp + (size_t)o * 4608 + n * 2) =
            (__bf16)(acc[mf][nf][r] + bv);
      }
    }
}

// ---------------------------------------------------------------------------
// Kernel 5 (v5): SWAPPED-operand flash attention.
//   S^T = mfma(K, Q): lane owns q = lr; kv = lk*4 + r + 16*sub (in regs).
//   Softmax fully in-register: in-lane max/sum + shfl_xor(16/32).
//   PV: A-operand = P in natural register order (pi-permutation applied to
//   BOTH operands: pi(lk*8+j) = lk*4+(j&3)+16*(j>>2), identity on A slots;
//   V B-frags read as 2x ds_read_b64 at pi'd kv offsets).
//   K/V double-buffered via global_load_lds, kv-tile 32, 1 barrier/iter.
//   LDS 64KB -> 2 blocks/CU.
// ---------------------------------------------------------------------------
__global__ __launch_bounds__(256, 2) void k_flash5(
    const char* __restrict__ Qw, const char* __restrict__ Kw, const char* __restrict__ Vw,
    const float* __restrict__ rgb, const float* __restrict__ tin,
    float* __restrict__ outp)
{
  // XCD-aware swizzle: XCD x owns pairs {2x, 2x+1}; 576 = 8 * 72 bijective
  const int F = blockIdx.x;
  const int xcd = F & 7, j = F >> 3;
  const int pair = xcd * 2 + (j >= 36 ? 1 : 0);
  const int qt = (j >= 36) ? j - 36 : j;
  const int a = pair >> 3, b = pair & 7;
  const char* __restrict__ Qp = Qw + (size_t)pair * N_ * 512;
  const char* __restrict__ Kp = Kw + (size_t)pair * N_ * 512;
  const char* __restrict__ Vp = Vw + (size_t)pair * C_ * 4608;
  const float* __restrict__ xsrc = (a ? tin : rgb) + (size_t)b * C_ * N_;
  float* __restrict__ op = outp + (size_t)(a * 8 + b) * C_ * N_;

  __shared__ alignas(16) char smem[65536];   // K0|K1 (16KB each) V0|V1 (16KB)

  const int t = threadIdx.x, lane = t & 63, w = t >> 6;
  const int lr = lane & 15, lk = lane >> 4;
  const int q0 = qt * 64;

  // Q fragments (B-operand): 16 rows per wave, in registers
  bf16x8 qf[8];
  {
    const int n = q0 + w * 16 + lr;
    const char* qrow = Qp + (size_t)n * 512;
    const int sw = (n & 7) << 4;
#pragma unroll
    for (int ks = 0; ks < 8; ++ks)
      qf[ks] = *(const bf16x8*)(qrow + ((ks * 64 + lk * 16) ^ sw));
  }

  f32x4 oacc[16] = {};
  float m_run = -1e30f, l_run = 0.f;

  // lane-constant V read offsets (row&3 == lr&3 since rows are cf*16+lr)
  const int vx0 = ((((lk >> 1) ^ (lr & 3)) << 4)) | ((lk & 1) << 3);
  const int vx1 = (((2 + (lk >> 1)) ^ (lr & 3)) << 4) | ((lk & 1) << 3);

#define STAGE_KV(T, CBUF)                                                     \
  {                                                                           \
    const char* Ks = Kp + (size_t)(T) * 32 * 512;                             \
    char* kd = smem + (CBUF) * 16384;                                         \
    _Pragma("unroll")                                                         \
    for (int s = 0; s < 4; ++s) {                                             \
      const int flat = s * 4096 + t * 16;                                     \
      gload16(Ks + flat, kd + flat);                                          \
    }                                                                         \
    const char* Vs = Vp + (size_t)(T) * 64;                                   \
    char* vd = smem + 32768 + (CBUF) * 16384;                                 \
    _Pragma("unroll")                                                         \
    for (int s = 0; s < 4; ++s) {                                             \
      const int flat = s * 4096 + t * 16;                                     \
      const int row = flat >> 6;                                              \
      const int slot = (flat >> 4) & 3;                                       \
      gload16(Vs + (size_t)row * 4608 + ((slot ^ (row & 3)) << 4), vd + flat);\
    }                                                                         \
  }

  STAGE_KV(0, 0);

  int c = 0;
  for (int kv = 0; kv < 72; ++kv) {
    __syncthreads();   // buf[c] staged; buf[c^1] free to overwrite
    if (kv + 1 < 72) STAGE_KV(kv + 1, c ^ 1);

    const char* Kl = smem + c * 16384;
    const char* Vl = smem + 32768 + c * 16384;

    // ---- S^T = K Q^T : output col = q = lr, row = kv = sub*16 + lk*4 + r
    f32x4 st[2] = {};
    __builtin_amdgcn_s_setprio(1);
#pragma unroll
    for (int sub = 0; sub < 2; ++sub) {
      const int row = sub * 16 + lr;       // kv row index (A-operand)
      const char* kr = Kl + row * 512;
      const int sw = (row & 7) << 4;
#pragma unroll
      for (int ks = 0; ks < 8; ++ks) {
        const bf16x8 kf = *(const bf16x8*)(kr + ((ks * 64 + lk * 16) ^ sw));
        st[sub] = __builtin_amdgcn_mfma_f32_16x16x32_bf16(kf, qf[ks], st[sub], 0, 0, 0);
      }
    }
    __builtin_amdgcn_s_setprio(0);

    // ---- in-register online softmax (per-lane scalar m/l for q = lr) ----
    float pm = fmaxf(fmaxf(fmaxf(st[0][0], st[0][1]), fmaxf(st[0][2], st[0][3])),
                     fmaxf(fmaxf(st[1][0], st[1][1]), fmaxf(st[1][2], st[1][3])));
    pm = fmaxf(pm, __shfl_xor(pm, 16));
    pm = fmaxf(pm, __shfl_xor(pm, 32));
    if (__any(pm > m_run + 8.f)) {
      const float mn = fmaxf(m_run, pm);
      const float sc = __expf(m_run - mn);
      m_run = mn;
      l_run *= sc;
#pragma unroll
      for (int r = 0; r < 4; ++r) {
        const float sr = __shfl(sc, lk * 4 + r);   // scale for q-row lk*4+r
#pragma unroll
        for (int cf = 0; cf < 16; ++cf) oacc[cf][r] *= sr;
      }
    }
    float p[8];
    float ps = 0.f;
#pragma unroll
    for (int s2 = 0; s2 < 2; ++s2)
#pragma unroll
      for (int r = 0; r < 4; ++r) {
        const float e = __expf(st[s2][r] - m_run);
        p[s2 * 4 + r] = e;
        ps += e;
      }
    ps += __shfl_xor(ps, 16);
    ps += __shfl_xor(ps, 32);
    l_run += ps;

    // P -> bf16 A-fragment (identity order under pi)
    bf16x8 pa;
#pragma unroll
    for (int jj = 0; jj < 8; ++jj) pa[jj] = (__bf16)p[jj];

    // ---- O += P @ V : B-frags = 2x b64 at pi'd kv offsets ----
    __builtin_amdgcn_s_setprio(1);
    const char* vb = Vl + lr * 64;
#pragma unroll
    for (int cf = 0; cf < 16; ++cf) {
      const char* vr = vb + cf * 1024;           // (cf*16+lr)*64
      const bf16x4 a0 = *(const bf16x4*)(vr + vx0);
      const bf16x4 a1 = *(const bf16x4*)(vr + vx1);
      bf16x8 vf;
#pragma unroll
      for (int jj = 0; jj < 4; ++jj) { vf[jj] = a0[jj]; vf[4 + jj] = a1[jj]; }
      oacc[cf] = __builtin_amdgcn_mfma_f32_16x16x32_bf16(pa, vf, oacc[cf], 0, 0, 0);
    }
    __builtin_amdgcn_s_setprio(0);
    c ^= 1;
  }

  // ---- epilogue: restage this block's 64 Q rows (32KB) into smem ----
  __syncthreads();
  {
    const char* Qsrc = Qp + (size_t)q0 * 512;
#pragma unroll
    for (int s = 0; s < 8; ++s) {
      const int flat = s * 4096 + t * 16;
      gload16(Qsrc + flat, smem + flat);
    }
  }
  __syncthreads();

  const float rl = 1.0f / l_run;
  float inv[4];
#pragma unroll
  for (int r = 0; r < 4; ++r) inv[r] = __shfl(rl, lk * 4 + r);

  const int nb = q0 + w * 16 + lk * 4;
  const int nl0 = w * 16 + lk * 4;
#pragma unroll
  for (int cf = 0; cf < 16; ++cf) {
    const int cc = cf * 16 + lr;
    const float4 xv = *(const float4*)(xsrc + (size_t)cc * N_ + nb);
    float vals[4];
#pragma unroll
    for (int r = 0; r < 4; ++r) {
      const int nl = nl0 + r;
      const float qv =
          (float)(*(const __bf16*)(smem + (size_t)nl * 512 + ((cc * 2) ^ ((nl & 7) << 4))));
      vals[r] = oacc[cf][r] * inv[r] + qv;
    }
    float4 ov;
    ov.x = vals[0] + xv.x; ov.y = vals[1] + xv.y;
    ov.z = vals[2] + xv.z; ov.w = vals[3] + xv.w;
    *(float4*)(op + (size_t)cc * N_ + nb) = ov;
  }
#undef STAGE_KV
}

// ---------------------------------------------------------------------------
extern "C" void kernel_launch(void* const* d_in, const int* in_sizes, int n_in,
                              void* d_out, int out_size, void* d_ws, size_t ws_size,
                              hipStream_t stream) {
  const float* rgb = (const float*)d_in[0];
  const float* tin = (const float*)d_in[1];
  const float* wq1 = (const float*)d_in[2];
  const float* bq1 = (const float*)d_in[3];
  const float* wk1 = (const float*)d_in[4];
  const float* bk1 = (const float*)d_in[5];
  const float* wv1 = (const float*)d_in[6];
  const float* bv1 = (const float*)d_in[7];
  const float* wq2 = (const float*)d_in[8];
  const float* bq2 = (const float*)d_in[9];
  const float* wk2 = (const float*)d_in[10];
  const float* bk2 = (const float*)d_in[11];
  const float* wv2 = (const float*)d_in[12];
  const float* bv2 = (const float*)d_in[13];

  char* ws = (char*)d_ws;
  char* xT = ws;
  char* Qw = ws + 2 * XT_BYTES;
  char* Kw = Qw + QK_BYTES;
  char* Vw = Kw + QK_BYTES;
  char* Wb = Vw + V_BYTES;

  k_transpose<<<dim3(36, 4, 16), 256, 0, stream>>>(rgb, tin, xT);
  k_wcvt<<<dim3(32, 6), 256, 0, stream>>>(wq1, wk1, wq2, wk2, wv1, wv2, Wb);
  k_proj_qk<<<dim3(72, 8, 4), 256, 0, stream>>>(xT, Wb, bq1, bk1, bq2, bk2, Qw, Kw);
  k_proj_v<<<dim3(72, 8, 2), 256, 0, stream>>>(xT, Wb, bv1, bv2, Vw);
  k_flash5<<<dim3(576), 256, 0, stream>>>(Qw, Kw, Vw, rgb, tin, (float*)d_out);
}

// Round 7
// 357.660 us; speedup vs baseline: 1.2447x; 1.2447x over previous
//
#include <hip/hip_runtime.h>
#include <hip/hip_bf16.h>
#include <cstdint>

#define B_ 8
#define C_ 256
#define N_ 2304
#define XT_BYTES ((size_t)B_ * N_ * C_ * 2)
#define QK_BYTES ((size_t)16 * N_ * C_ * 2)
#define V_BYTES  ((size_t)16 * C_ * N_ * 2)

typedef __bf16 bf16x8 __attribute__((ext_vector_type(8)));
typedef float  f32x4  __attribute__((ext_vector_type(4)));
typedef float  f32x16 __attribute__((ext_vector_type(16)));
static_assert(sizeof(bf16x8) == 16, "");

// async global->LDS, 16B per lane (dest = wave-uniform base + lane*16)
__device__ __forceinline__ void gload16(const void* g, void* l) {
  __builtin_amdgcn_global_load_lds(
      reinterpret_cast<const __attribute__((address_space(1))) uint32_t*>(
          reinterpret_cast<uintptr_t>(g)),
      reinterpret_cast<__attribute__((address_space(3))) uint32_t*>(
          reinterpret_cast<uintptr_t>(l)),
      16, 0, 0);
}

// ---------------------------------------------------------------------------
// Kernel 1: transpose + cvt: x[b][i][n] f32 -> xT[b][n][i] bf16, swizzled rows
// ---------------------------------------------------------------------------
__global__ __launch_bounds__(256) void k_transpose(
    const float* __restrict__ rgb, const float* __restrict__ tin,
    char* __restrict__ xT)
{
  const int nt = blockIdx.x;
  const int it = blockIdx.y;
  const int z  = blockIdx.z;
  const int src = z >> 3, b = z & 7;
  const float* __restrict__ in = (src ? tin : rgb) + (size_t)b * C_ * N_;
  char* __restrict__ out = xT + (size_t)src * XT_BYTES + (size_t)b * N_ * 512;
  const int i0 = it * 64, n0 = nt * 64;
  __shared__ float raw[64 * 65];
  const int t = threadIdx.x;
  const int rr = t >> 4;
  const int cc = t & 15;
#pragma unroll
  for (int j = 0; j < 4; ++j) {
    const int ii = rr + 16 * j;
    const float4 v = *(const float4*)(in + (size_t)(i0 + ii) * N_ + n0 + cc * 4);
    float* rp = &raw[ii * 65 + cc * 4];
    rp[0] = v.x; rp[1] = v.y; rp[2] = v.z; rp[3] = v.w;
  }
  __syncthreads();
#pragma unroll
  for (int k = 0; k < 4; ++k) {
    const int nl = rr + 16 * k;
    const int n = n0 + nl;
    union { __bf16 h[4]; uint2 u; } pk;
#pragma unroll
    for (int e = 0; e < 4; ++e)
      pk.h[e] = (__bf16)raw[(cc * 4 + e) * 65 + nl];
    const int cb = ((i0 + cc * 4) * 2) ^ ((n & 7) << 4);
    *(uint2*)(out + (size_t)n * 512 + cb) = pk.u;
  }
}

// ---------------------------------------------------------------------------
// Kernel 2: weights f32 -> bf16 swizzled rows (order wq1,wk1,wq2,wk2,wv1,wv2)
// ---------------------------------------------------------------------------
__global__ __launch_bounds__(256) void k_wcvt(
    const float* __restrict__ w0, const float* __restrict__ w1,
    const float* __restrict__ w2, const float* __restrict__ w3,
    const float* __restrict__ w4, const float* __restrict__ w5,
    char* __restrict__ Wb)
{
  const int widx = blockIdx.y;
  const float* w = widx == 0 ? w0 : widx == 1 ? w1 : widx == 2 ? w2
                 : widx == 3 ? w3 : widx == 4 ? w4 : w5;
  const int t = threadIdx.x;
  const int row = blockIdx.x * 8 + (t >> 5);
  const int c8 = (t & 31) * 8;
  const float4 v0 = *(const float4*)(w + row * 256 + c8);
  const float4 v1 = *(const float4*)(w + row * 256 + c8 + 4);
  union { __bf16 h[8]; uint4 u; } pk;
  pk.h[0] = (__bf16)v0.x; pk.h[1] = (__bf16)v0.y; pk.h[2] = (__bf16)v0.z; pk.h[3] = (__bf16)v0.w;
  pk.h[4] = (__bf16)v1.x; pk.h[5] = (__bf16)v1.y; pk.h[6] = (__bf16)v1.z; pk.h[7] = (__bf16)v1.w;
  const int cb = (c8 * 2) ^ ((row & 7) << 4);
  *(uint4*)(Wb + (size_t)(widx * 256 + row) * 512 + cb) = pk.u;
}

// ---------------------------------------------------------------------------
// Kernel 3: Q/K projection (unchanged, validated)
// ---------------------------------------------------------------------------
__global__ __launch_bounds__(256, 2) void k_proj_qk(
    const char* __restrict__ xT, const char* __restrict__ Wb,
    const float* __restrict__ bq1, const float* __restrict__ bk1,
    const float* __restrict__ bq2, const float* __restrict__ bk2,
    char* __restrict__ Qw, char* __restrict__ Kw)
{
  const int z = blockIdx.z;
  const int b = blockIdx.y;
  const int ntile = blockIdx.x >> 2, otile = blockIdx.x & 3;
  const int n0 = ntile * 128, o0 = otile * 64;
  const int srcT = (z == 1 || z == 2);
  const char* __restrict__ xp = xT + (size_t)srcT * XT_BYTES + (size_t)b * N_ * 512;
  const char* __restrict__ Wp = Wb + (size_t)z * C_ * 512;
  const float* __restrict__ bias = z == 0 ? bq1 : z == 1 ? bk1 : z == 2 ? bq2 : bk2;
  char* __restrict__ outp = ((z == 0 || z == 2) ? Qw : Kw)
                            + (size_t)((z >= 2 ? 8 : 0) + b) * N_ * 512;

  __shared__ alignas(16) char Alds[128 * 128];
  __shared__ alignas(16) char Wlds[64 * 128];
  const int t = threadIdx.x, lane = t & 63, wid = t >> 6;
  const int wm = wid >> 1, wn = wid & 1;
  const int lr = lane & 15, lk = lane >> 4;
  f32x4 acc[4][2] = {};

  for (int ko = 0; ko < 4; ++ko) {
    const int ib = ko * 128;
    __syncthreads();
#pragma unroll
    for (int s = 0; s < 4; ++s) {
      const int flat = s * 4096 + t * 16;
      *(uint4*)(Alds + flat) =
          *(const uint4*)(xp + (size_t)(n0 + (flat >> 7)) * 512 + ib + (flat & 127));
    }
#pragma unroll
    for (int s = 0; s < 2; ++s) {
      const int flat = s * 4096 + t * 16;
      *(uint4*)(Wlds + flat) =
          *(const uint4*)(Wp + (size_t)(o0 + (flat >> 7)) * 512 + ib + (flat & 127));
    }
    __syncthreads();
#pragma unroll
    for (int ks = 0; ks < 2; ++ks) {
      bf16x8 af[4], bfr[2];
#pragma unroll
      for (int mf = 0; mf < 4; ++mf) {
        const int row = wm * 64 + mf * 16 + lr;
        af[mf] = *(const bf16x8*)(Alds + row * 128 + ((ks * 64 + lk * 16) ^ ((row & 7) << 4)));
      }
#pragma unroll
      for (int nf = 0; nf < 2; ++nf) {
        const int row = wn * 32 + nf * 16 + lr;
        bfr[nf] = *(const bf16x8*)(Wlds + row * 128 + ((ks * 64 + lk * 16) ^ ((row & 7) << 4)));
      }
#pragma unroll
      for (int mf = 0; mf < 4; ++mf)
#pragma unroll
        for (int nf = 0; nf < 2; ++nf)
          acc[mf][nf] = __builtin_amdgcn_mfma_f32_16x16x32_bf16(af[mf], bfr[nf], acc[mf][nf], 0, 0, 0);
    }
  }
#pragma unroll
  for (int nf = 0; nf < 2; ++nf) {
    const int c = o0 + wn * 32 + nf * 16 + lr;
    const float bv = bias[c];
#pragma unroll
    for (int mf = 0; mf < 4; ++mf)
#pragma unroll
      for (int r = 0; r < 4; ++r) {
        const int n = n0 + wm * 64 + mf * 16 + lk * 4 + r;
        *(__bf16*)(outp + (size_t)n * 512 + ((c * 2) ^ ((n & 7) << 4))) =
            (__bf16)(acc[mf][nf][r] + bv);
      }
  }
}

// ---------------------------------------------------------------------------
// Kernel 4: V projection, stored transposed [c][n], UNSWIZZLED (validated)
// ---------------------------------------------------------------------------
__global__ __launch_bounds__(256, 2) void k_proj_v(
    const char* __restrict__ xT, const char* __restrict__ Wb,
    const float* __restrict__ bv1, const float* __restrict__ bv2,
    char* __restrict__ Vw)
{
  const int z = blockIdx.z;
  const int b = blockIdx.y;
  const int ntile = blockIdx.x >> 2, otile = blockIdx.x & 3;
  const int n0 = ntile * 128, o0 = otile * 64;
  const char* __restrict__ xp = xT + (size_t)(z == 0 ? 1 : 0) * XT_BYTES + (size_t)b * N_ * 512;
  const char* __restrict__ Wp = Wb + (size_t)(4 + z) * C_ * 512;
  const float* __restrict__ bias = z ? bv2 : bv1;
  char* __restrict__ outp = Vw + (size_t)(z * 8 + b) * C_ * 4608;

  __shared__ alignas(16) char Xlds[128 * 128];
  __shared__ alignas(16) char Wlds[64 * 128];
  const int t = threadIdx.x, lane = t & 63, wid = t >> 6;
  const int wm = wid >> 1, wn = wid & 1;
  const int lr = lane & 15, lk = lane >> 4;
  f32x4 acc[2][4] = {};

  for (int ko = 0; ko < 4; ++ko) {
    const int ib = ko * 128;
    __syncthreads();
#pragma unroll
    for (int s = 0; s < 4; ++s) {
      const int flat = s * 4096 + t * 16;
      *(uint4*)(Xlds + flat) =
          *(const uint4*)(xp + (size_t)(n0 + (flat >> 7)) * 512 + ib + (flat & 127));
    }
#pragma unroll
    for (int s = 0; s < 2; ++s) {
      const int flat = s * 4096 + t * 16;
      *(uint4*)(Wlds + flat) =
          *(const uint4*)(Wp + (size_t)(o0 + (flat >> 7)) * 512 + ib + (flat & 127));
    }
    __syncthreads();
#pragma unroll
    for (int ks = 0; ks < 2; ++ks) {
      bf16x8 af[2], bfr[4];
#pragma unroll
      for (int mf = 0; mf < 2; ++mf) {
        const int row = wm * 32 + mf * 16 + lr;
        af[mf] = *(const bf16x8*)(Wlds + row * 128 + ((ks * 64 + lk * 16) ^ ((row & 7) << 4)));
      }
#pragma unroll
      for (int nf = 0; nf < 4; ++nf) {
        const int row = wn * 64 + nf * 16 + lr;
        bfr[nf] = *(const bf16x8*)(Xlds + row * 128 + ((ks * 64 + lk * 16) ^ ((row & 7) << 4)));
      }
#pragma unroll
      for (int mf = 0; mf < 2; ++mf)
#pragma unroll
        for (int nf = 0; nf < 4; ++nf)
          acc[mf][nf] = __builtin_amdgcn_mfma_f32_16x16x32_bf16(af[mf], bfr[nf], acc[mf][nf], 0, 0, 0);
    }
  }
#pragma unroll
  for (int mf = 0; mf < 2; ++mf)
#pragma unroll
    for (int r = 0; r < 4; ++r) {
      const int o = o0 + wm * 32 + mf * 16 + lk * 4 + r;
      const float bv = bias[o];
#pragma unroll
      for (int nf = 0; nf < 4; ++nf) {
        const int n = n0 + wn * 64 + nf * 16 + lr;
        *(__bf16*)(outp + (size_t)o * 4608 + n * 2) =
            (__bf16)(acc[mf][nf][r] + bv);
      }
    }
}

// ---------------------------------------------------------------------------
// Kernel 5 (v6): flash attention, R1 QK + c-split PV with 32x32x16 MFMAs.
//   QK: wave w owns q-rows [16w,16w+16), Q in regs (R1, validated).
//   PV: block-level P[64q x 64kv] @ V[64kv x 256c]; wave w owns c-slice
//       [64w, 64w+64) for ALL 64 q. V read ONCE per block per tile.
//   P / per-q scale / 1/l cross waves via LDS; deferred rescale flag-guarded.
//   LDS: K 32KB | V 32KB | P 8KB | scale/l/flag ~0.6KB = ~73KB -> 2 blocks/CU.
// ---------------------------------------------------------------------------
__global__ __launch_bounds__(256) void k_flash6(
    const char* __restrict__ Qw, const char* __restrict__ Kw, const char* __restrict__ Vw,
    const float* __restrict__ rgb, const float* __restrict__ tin,
    float* __restrict__ outp)
{
  const int F = blockIdx.x;
  const int xcd = F & 7, j = F >> 3;
  const int pair = xcd * 2 + (j >= 36 ? 1 : 0);
  const int qt = (j >= 36) ? j - 36 : j;
  const int a = pair >> 3, b = pair & 7;
  const char* __restrict__ Qp = Qw + (size_t)pair * N_ * 512;
  const char* __restrict__ Kp = Kw + (size_t)pair * N_ * 512;
  const char* __restrict__ Vp = Vw + (size_t)pair * C_ * 4608;
  const float* __restrict__ xsrc = (a ? tin : rgb) + (size_t)b * C_ * N_;
  float* __restrict__ op = outp + (size_t)(a * 8 + b) * C_ * N_;

  __shared__ alignas(16) char smem[74752];
  char* Klds = smem;              // 64 kv x 512B (pre-swizzled rows)
  char* Vlds = smem + 32768;      // 256 c  x 128B (XOR-swizzled)
  char* Plds = smem + 65536;      // 64 q   x 128B (XOR-swizzled)
  float* scaleL = (float*)(smem + 73728);  // 64 per-q rescale factors
  float* lL     = (float*)(smem + 73984);  // 64 per-q softmax denoms
  int*   flagL  = (int*)(smem + 74240);

  const int t = threadIdx.x, lane = t & 63, w = t >> 6;
  const int lr = lane & 15, lk = lane >> 4;
  const int l31 = lane & 31, hi = lane >> 5;
  const int q0 = qt * 64;

  // Q fragments: 16 rows per wave, in registers (R1)
  bf16x8 qf[8];
  {
    const int n = q0 + w * 16 + lr;
    const char* qrow = Qp + (size_t)n * 512;
    const int sw = (n & 7) << 4;
#pragma unroll
    for (int ks = 0; ks < 8; ++ks)
      qf[ks] = *(const bf16x8*)(qrow + ((ks * 64 + lk * 16) ^ sw));
  }

  f32x16 oacc[2][2] = {};   // [mq][nc]
  float m_run[4], l_run[4];
#pragma unroll
  for (int r = 0; r < 4; ++r) { m_run[r] = -1e30f; l_run[r] = 0.f; }

  if (t == 0) *flagL = 0;

#define STAGE_KV(T)                                                           \
  {                                                                           \
    const char* Ks = Kp + (size_t)(T) * 32768;                                \
    _Pragma("unroll")                                                         \
    for (int s = 0; s < 8; ++s) {                                             \
      const int flat = s * 4096 + t * 16;                                     \
      gload16(Ks + flat, Klds + flat);                                        \
    }                                                                         \
    const char* Vs = Vp + (size_t)(T) * 128;                                  \
    _Pragma("unroll")                                                         \
    for (int s = 0; s < 8; ++s) {                                             \
      const int flat = s * 4096 + t * 16;                                     \
      const int cR = flat >> 7;                                               \
      const int chunk = (flat >> 4) & 7;                                      \
      gload16(Vs + (size_t)cR * 4608 + ((chunk ^ (cR & 7)) << 4),             \
              Vlds + flat);                                                   \
    }                                                                         \
  }

  STAGE_KV(0);

  for (int kv = 0; kv < 36; ++kv) {
    __syncthreads();   // A: staging done (+ flag reset visible)

    // ---- S = Q K^T (wave's 16 q x 64 kv), R1-identical ----
    f32x4 s4[4] = {};
    __builtin_amdgcn_s_setprio(1);
#pragma unroll
    for (int mf = 0; mf < 4; ++mf) {
      const int row = mf * 16 + lr;
      const char* kr = Klds + row * 512;
      const int sw = (row & 7) << 4;
#pragma unroll
      for (int ks = 0; ks < 8; ++ks) {
        const bf16x8 kf = *(const bf16x8*)(kr + ((ks * 64 + lk * 16) ^ sw));
        s4[mf] = __builtin_amdgcn_mfma_f32_16x16x32_bf16(qf[ks], kf, s4[mf], 0, 0, 0);
      }
    }
    __builtin_amdgcn_s_setprio(0);

    // ---- online softmax (wave-local q rows), deferred rescale ----
    float pmax[4];
#pragma unroll
    for (int r = 0; r < 4; ++r) {
      float m0 = fmaxf(fmaxf(s4[0][r], s4[1][r]), fmaxf(s4[2][r], s4[3][r]));
      m0 = fmaxf(m0, __shfl_xor(m0, 1));
      m0 = fmaxf(m0, __shfl_xor(m0, 2));
      m0 = fmaxf(m0, __shfl_xor(m0, 4));
      m0 = fmaxf(m0, __shfl_xor(m0, 8));
      pmax[r] = m0;
    }
    bool need = false;
#pragma unroll
    for (int r = 0; r < 4; ++r) need |= (pmax[r] > m_run[r] + 8.f);
    float scv[4];
    if (__any(need)) {
#pragma unroll
      for (int r = 0; r < 4; ++r) {
        const float mn = fmaxf(m_run[r], pmax[r]);
        const float sc = __expf(m_run[r] - mn);
        m_run[r] = mn;
        l_run[r] *= sc;
        scv[r] = sc;
      }
      if (lane == 0) *flagL = 1;
    } else {
#pragma unroll
      for (int r = 0; r < 4; ++r) scv[r] = 1.0f;
    }
    if (lr == 0) {
      float4 s4v; s4v.x = scv[0]; s4v.y = scv[1]; s4v.z = scv[2]; s4v.w = scv[3];
      *(float4*)(scaleL + w * 16 + lk * 4) = s4v;
    }

    // ---- P = exp(S - m) -> Plds[q][kv] (XOR-swizzled), row-sum to l ----
    {
      float psum[4] = {0.f, 0.f, 0.f, 0.f};
#pragma unroll
      for (int mf = 0; mf < 4; ++mf)
#pragma unroll
        for (int r = 0; r < 4; ++r) {
          const float p = __expf(s4[mf][r] - m_run[r]);
          psum[r] += p;
          const int q = w * 16 + lk * 4 + r;
          const int kvc = mf * 16 + lr;
          *(__bf16*)(Plds + q * 128 + ((kvc * 2) ^ ((q & 7) << 4))) = (__bf16)p;
        }
#pragma unroll
      for (int r = 0; r < 4; ++r) {
        float s0 = psum[r];
        s0 += __shfl_xor(s0, 1);
        s0 += __shfl_xor(s0, 2);
        s0 += __shfl_xor(s0, 4);
        s0 += __shfl_xor(s0, 8);
        l_run[r] += s0;
      }
    }
    __syncthreads();   // B: P + scale + flag ready

    // ---- apply deferred rescale to c-split accumulators (rare) ----
    if (*flagL) {
#pragma unroll
      for (int mq = 0; mq < 2; ++mq)
#pragma unroll
        for (int rg = 0; rg < 4; ++rg) {
          const float4 sc4 = *(const float4*)(scaleL + mq * 32 + 8 * rg + 4 * hi);
#pragma unroll
          for (int nc = 0; nc < 2; ++nc) {
            oacc[mq][nc][rg * 4 + 0] *= sc4.x;
            oacc[mq][nc][rg * 4 + 1] *= sc4.y;
            oacc[mq][nc][rg * 4 + 2] *= sc4.z;
            oacc[mq][nc][rg * 4 + 3] *= sc4.w;
          }
        }
    }

    // ---- O += P @ V : 32x32x16, wave owns c in [64w, 64w+64) ----
    __builtin_amdgcn_s_setprio(1);
#pragma unroll
    for (int ks = 0; ks < 4; ++ks) {
      const int kb = (ks * 32 + hi * 16);
      bf16x8 pa[2], vf[2];
#pragma unroll
      for (int mq = 0; mq < 2; ++mq) {
        const int q = mq * 32 + l31;
        pa[mq] = *(const bf16x8*)(Plds + q * 128 + (kb ^ ((q & 7) << 4)));
      }
#pragma unroll
      for (int nc = 0; nc < 2; ++nc) {
        const int cl = w * 64 + nc * 32 + l31;
        vf[nc] = *(const bf16x8*)(Vlds + cl * 128 + (kb ^ ((cl & 7) << 4)));
      }
#pragma unroll
      for (int mq = 0; mq < 2; ++mq)
#pragma unroll
        for (int nc = 0; nc < 2; ++nc)
          oacc[mq][nc] = __builtin_amdgcn_mfma_f32_32x32x16_bf16(pa[mq], vf[nc], oacc[mq][nc], 0, 0, 0);
    }
    __builtin_amdgcn_s_setprio(0);
    __syncthreads();   // C: everyone done with V, P
    if (t == 0) *flagL = 0;            // reset before next tile's barrier A
    if (kv + 1 < 36) STAGE_KV(kv + 1);
  }

  // ---- epilogue ----
  if (lr == 0) {
    float4 l4; l4.x = l_run[0]; l4.y = l_run[1]; l4.z = l_run[2]; l4.w = l_run[3];
    *(float4*)(lL + w * 16 + lk * 4) = l4;
  }
  __syncthreads();   // l visible; Klds free
  {
    const char* Qsrc = Qp + (size_t)q0 * 512;
#pragma unroll
    for (int s = 0; s < 8; ++s) {
      const int flat = s * 4096 + t * 16;
      gload16(Qsrc + flat, Klds + flat);
    }
  }
  __syncthreads();

#pragma unroll
  for (int mq = 0; mq < 2; ++mq)
#pragma unroll
    for (int rg = 0; rg < 4; ++rg) {
      const int qb = mq * 32 + 8 * rg + 4 * hi;   // 4 consecutive q rows
      const float4 l4 = *(const float4*)(lL + qb);
      float inv[4];
      inv[0] = 1.0f / l4.x; inv[1] = 1.0f / l4.y;
      inv[2] = 1.0f / l4.z; inv[3] = 1.0f / l4.w;
#pragma unroll
      for (int nc = 0; nc < 2; ++nc) {
        const int cl = w * 64 + nc * 32 + l31;
        const float4 xv = *(const float4*)(xsrc + (size_t)cl * N_ + q0 + qb);
        float vals[4];
#pragma unroll
        for (int e = 0; e < 4; ++e) {
          const int nl = qb + e;
          const float qv =
              (float)(*(const __bf16*)(Klds + (size_t)nl * 512 + ((cl * 2) ^ ((nl & 7) << 4))));
          vals[e] = oacc[mq][nc][rg * 4 + e] * inv[e] + qv;
        }
        float4 ov;
        ov.x = vals[0] + xv.x; ov.y = vals[1] + xv.y;
        ov.z = vals[2] + xv.z; ov.w = vals[3] + xv.w;
        *(float4*)(op + (size_t)cl * N_ + q0 + qb) = ov;
      }
    }
#undef STAGE_KV
}

// ---------------------------------------------------------------------------
extern "C" void kernel_launch(void* const* d_in, const int* in_sizes, int n_in,
                              void* d_out, int out_size, void* d_ws, size_t ws_size,
                              hipStream_t stream) {
  const float* rgb = (const float*)d_in[0];
  const float* tin = (const float*)d_in[1];
  const float* wq1 = (const float*)d_in[2];
  const float* bq1 = (const float*)d_in[3];
  const float* wk1 = (const float*)d_in[4];
  const float* bk1 = (const float*)d_in[5];
  const float* wv1 = (const float*)d_in[6];
  const float* bv1 = (const float*)d_in[7];
  const float* wq2 = (const float*)d_in[8];
  const float* bq2 = (const float*)d_in[9];
  const float* wk2 = (const float*)d_in[10];
  const float* bk2 = (const float*)d_in[11];
  const float* wv2 = (const float*)d_in[12];
  const float* bv2 = (const float*)d_in[13];

  char* ws = (char*)d_ws;
  char* xT = ws;
  char* Qw = ws + 2 * XT_BYTES;
  char* Kw = Qw + QK_BYTES;
  char* Vw = Kw + QK_BYTES;
  char* Wb = Vw + V_BYTES;

  k_transpose<<<dim3(36, 4, 16), 256, 0, stream>>>(rgb, tin, xT);
  k_wcvt<<<dim3(32, 6), 256, 0, stream>>>(wq1, wk1, wq2, wk2, wv1, wv2, Wb);
  k_proj_qk<<<dim3(72, 8, 4), 256, 0, stream>>>(xT, Wb, bq1, bk1, bq2, bk2, Qw, Kw);
  k_proj_v<<<dim3(72, 8, 2), 256, 0, stream>>>(xT, Wb, bv1, bv2, Vw);
  k_flash6<<<dim3(576), 256, 0, stream>>>(Qw, Kw, Vw, rgb, tin, (float*)d_out);
}